// Round 17
// baseline (815.682 us; speedup 1.0000x reference)
//
#include <hip/hip_runtime.h>
#include <hip/hip_bf16.h>
#include <math.h>

#define N_NODES 50000
#define N_EDGES 640000
#define N_GRAPHS 2000
#define FN 64
#define FE 16
#define H 128
#define NL 2
#define SCB 1024

typedef __attribute__((ext_vector_type(8))) short short8;
typedef __attribute__((ext_vector_type(4))) float float4v;
typedef __attribute__((ext_vector_type(2))) float float2v;
typedef __hip_bfloat16 bf16;

// ---------------- static workspace ----------------
static constexpr size_t AL = 256;
static constexpr size_t alup(size_t x) { return (x + AL - 1) & ~(AL - 1); }

static constexpr size_t SZ_HB    = (size_t)N_NODES * H * 2;
static constexpr size_t SZ_XB    = (size_t)N_NODES * FN * 2;
static constexpr size_t SZ_PQMB  = (size_t)N_NODES * 384 * 2;
static constexpr size_t SZ_GHX   = (size_t)N_NODES * 384 * 2;
static constexpr size_t SZ_HW1B  = (size_t)N_NODES * H * 2;
static constexpr size_t SZ_AGB   = (size_t)N_NODES * H * 2;
static constexpr size_t SZ_NF    = (size_t)N_NODES * 4;
static constexpr size_t SZ_WT    = (size_t)768 * 128 * 2;
static constexpr size_t SZ_WIHT  = (size_t)384 * 128 * 2;
static constexpr size_t SZ_EMBT  = (size_t)128 * 64 * 2;
static constexpr size_t SZ_WPK   = (size_t)16 * 256 * 4;
static constexpr size_t SZ_BBIG  = (size_t)768 * 4;
static constexpr size_t SZ_G128  = (size_t)N_GRAPHS * 128 * 4;
static constexpr size_t SZ_G384  = (size_t)N_GRAPHS * 384 * 4;
static constexpr size_t SZ_GF    = (size_t)N_GRAPHS * 4;
static constexpr size_t SZ_CSRC  = (size_t)N_EDGES * 4 + 64;
static constexpr size_t SZ_EAC   = (size_t)N_EDGES * 64 + 64;
static constexpr size_t SZ_BSUM  = 256 * 4;

static constexpr size_t OFF_H0B   = 0;
static constexpr size_t OFF_H1B   = alup(OFF_H0B + SZ_HB);
static constexpr size_t OFF_XB    = alup(OFF_H1B + SZ_HB);
static constexpr size_t OFF_PQMB  = alup(OFF_XB + SZ_XB);
static constexpr size_t OFF_GHX   = alup(OFF_PQMB + SZ_PQMB);
static constexpr size_t OFF_HW1B  = alup(OFF_GHX + SZ_GHX);
static constexpr size_t OFF_AGB   = alup(OFF_HW1B + SZ_HW1B);
static constexpr size_t OFF_ES    = alup(OFF_AGB + SZ_AGB);
static constexpr size_t OFF_WT    = alup(OFF_ES + SZ_NF);
static constexpr size_t OFF_WIHT  = alup(OFF_WT + SZ_WT);
static constexpr size_t OFF_EMBT  = alup(OFF_WIHT + SZ_WIHT);
static constexpr size_t OFF_WPK   = alup(OFF_EMBT + SZ_EMBT);
static constexpr size_t OFF_BBIG  = alup(OFF_WPK + SZ_WPK);
static constexpr size_t OFF_G0    = alup(OFF_BBIG + SZ_BBIG);
static constexpr size_t OFF_GA    = alup(OFF_G0 + SZ_G128);
static constexpr size_t OFF_CTX   = alup(OFF_GA + SZ_G128);
static constexpr size_t OFF_GICTX = alup(OFF_CTX + SZ_G128);
static constexpr size_t OFF_GHR   = alup(OFF_GICTX + SZ_G384);
static constexpr size_t OFF_DEG   = alup(OFF_GHR + SZ_G384);
static constexpr size_t OFF_CUR   = alup(OFF_DEG + SZ_NF);
static constexpr size_t OFF_GSUM  = alup(OFF_CUR + SZ_NF);
static constexpr size_t SZ_ZERO   = OFF_GSUM + SZ_GF - OFF_DEG;
static constexpr size_t OFF_OFFS  = alup(OFF_GSUM + SZ_GF);
static constexpr size_t OFF_GOFFS = alup(OFF_OFFS + SZ_NF + 4);
static constexpr size_t OFF_CSRC  = alup(OFF_GOFFS + SZ_GF + 4);
static constexpr size_t OFF_EAC   = alup(OFF_CSRC + SZ_CSRC);
static constexpr size_t OFF_BSUM  = alup(OFF_EAC + SZ_EAC);
static constexpr size_t TOTAL_WS  = alup(OFF_BSUM + SZ_BSUM);

__device__ unsigned char g_afp_ws[TOTAL_WS];

__device__ inline float bf2f(unsigned short u) {
    unsigned int x = ((unsigned int)u) << 16;
    return __uint_as_float(x);
}
__device__ inline unsigned short f2bfu(float f) {
    bf16 b = __float2bfloat16(f);
    return *(unsigned short*)&b;
}

// ---------------- MFMA bf16 GEMM (compile-time K), LDS-staged coalesced epilogue ----
// mode bit0: relu. bit1: split768 (plain): gc<384 -> Cb[r*384+gc], else Cb2[r*384+gc-384].
// bit3: plain bf16 (Cb, stride Ncol). All outputs bf16.
template<int K>
__global__ __launch_bounds__(256) void gemm_mfma(
    const bf16* __restrict__ Abf, const bf16* __restrict__ Btbf,
    const float* __restrict__ bias,
    bf16* __restrict__ Cb, bf16* __restrict__ Cb2,
    int M, int Ncol, int mode)
{
    __shared__ unsigned short ctile[64][72];
    const unsigned short* A  = (const unsigned short*)Abf;
    const unsigned short* Bt = (const unsigned short*)Btbf;
    const int l  = threadIdx.x & 63;
    const int w  = threadIdx.x >> 6;
    const int wm = w >> 1, wn = w & 1;
    const int rowb = blockIdx.x * 64;
    const int row0 = rowb + wm * 32;
    const int col0 = blockIdx.y * 64 + wn * 32;
    const int lr = l & 15;
    const int lk = (l >> 4) * 8;
    float4v acc[2][2] = {};
    #pragma unroll
    for (int k0 = 0; k0 < K; k0 += 32) {
        short8 a[2], b[2];
        #pragma unroll
        for (int i = 0; i < 2; ++i) {
            int r = row0 + i * 16 + lr;
            if (r >= M) r = M - 1;
            a[i] = *(const short8*)(A + (size_t)r * K + k0 + lk);
        }
        #pragma unroll
        for (int j = 0; j < 2; ++j) {
            int c = col0 + j * 16 + lr;
            b[j] = *(const short8*)(Bt + (size_t)c * K + k0 + lk);
        }
        #pragma unroll
        for (int i = 0; i < 2; ++i)
            #pragma unroll
            for (int j = 0; j < 2; ++j)
                acc[i][j] = __builtin_amdgcn_mfma_f32_16x16x32_bf16(a[i], b[j], acc[i][j], 0, 0, 0);
    }
    const int orow = (l >> 4) * 4;
    const int ocol = l & 15;
    #pragma unroll
    for (int i = 0; i < 2; ++i) {
        #pragma unroll
        for (int j = 0; j < 2; ++j) {
            const int lc = wn * 32 + j * 16 + ocol;
            const int gc = blockIdx.y * 64 + lc;
            const float bi = bias ? bias[gc] : 0.f;
            #pragma unroll
            for (int r = 0; r < 4; ++r) {
                const int lrow = wm * 32 + i * 16 + orow + r;
                float v = acc[i][j][r] + bi;
                if (mode & 1) v = fmaxf(v, 0.f);
                ctile[lrow][lc] = f2bfu(v);
            }
        }
    }
    __syncthreads();
    unsigned short* CbU  = (unsigned short*)Cb;
    unsigned short* Cb2U = (unsigned short*)Cb2;
    for (int u = threadIdx.x; u < 512; u += 256) {
        const int row = u >> 3, ck = (u & 7) * 8;
        const int gr = rowb + row;
        if (gr >= M) continue;
        short8 val = *(const short8*)&ctile[row][ck];
        const int gc = blockIdx.y * 64 + ck;
        if (mode & 2) {
            if (gc < 384) *(short8*)(CbU + (size_t)gr * 384 + gc) = val;
            else          *(short8*)(Cb2U + (size_t)gr * 384 + (gc - 384)) = val;
        } else {
            *(short8*)(CbU + (size_t)gr * Ncol + gc) = val;
        }
    }
}

// ---------------- fused gi-GEMM + GRU (bf16 h), LDS-staged stores ----------------
__global__ __launch_bounds__(256) void gemm_gru(
    const bf16* __restrict__ Abf, const bf16* __restrict__ Btbf,
    const float* __restrict__ bias, const bf16* __restrict__ ghb,
    const bf16* __restrict__ holdb, bf16* __restrict__ hnewb, int M)
{
    __shared__ unsigned short htile[64][136];
    const unsigned short* A  = (const unsigned short*)Abf;
    const unsigned short* Bt = (const unsigned short*)Btbf;
    const unsigned short* gh = (const unsigned short*)ghb;
    const unsigned short* hold = (const unsigned short*)holdb;
    const int l  = threadIdx.x & 63;
    const int w  = threadIdx.x >> 6;
    const int rowb = blockIdx.x * 64;
    const int row0 = rowb + w * 16;
    const int lr = l & 15;
    const int lk = (l >> 4) * 8;
    float4v acc[24] = {};
    #pragma unroll
    for (int k0 = 0; k0 < 128; k0 += 32) {
        int r = row0 + lr;
        if (r >= M) r = M - 1;
        short8 a = *(const short8*)(A + (size_t)r * 128 + k0 + lk);
        #pragma unroll
        for (int j = 0; j < 24; ++j) {
            short8 b = *(const short8*)(Bt + (size_t)(j * 16 + lr) * 128 + k0 + lk);
            acc[j] = __builtin_amdgcn_mfma_f32_16x16x32_bf16(a, b, acc[j], 0, 0, 0);
        }
    }
    const int orow = (l >> 4) * 4;
    const int ocol = l & 15;
    #pragma unroll
    for (int a_ = 0; a_ < 8; ++a_) {
        const int c = a_ * 16 + ocol;
        const float bir = bias[c], biz = bias[c + 128], bin = bias[c + 256];
        #pragma unroll
        for (int r = 0; r < 4; ++r) {
            const int gr = row0 + orow + r;
            const int grc = (gr >= M) ? (M - 1) : gr;
            float ir = acc[a_][r] + bir;
            float iz = acc[a_ + 8][r] + biz;
            float in = acc[a_ + 16][r] + bin;
            const unsigned short* ghp = gh + (size_t)grc * 384;
            float hr = bf2f(ghp[c]);
            float hz = bf2f(ghp[128 + c]);
            float hn = bf2f(ghp[256 + c]);
            float rg = 1.f / (1.f + __expf(-(ir + hr)));
            float zg = 1.f / (1.f + __expf(-(iz + hz)));
            float ng = tanhf(in + rg * hn);
            float hv = bf2f(hold[(size_t)grc * 128 + c]);
            float o = (1.f - zg) * ng + zg * hv;
            htile[w * 16 + orow + r][c] = f2bfu(o);
        }
    }
    __syncthreads();
    unsigned short* outU = (unsigned short*)hnewb;
    for (int u = threadIdx.x; u < 1024; u += 256) {
        const int row = u >> 4, ck = (u & 15) * 8;
        const int gr = rowb + row;
        if (gr >= M) continue;
        short8 val = *(const short8*)&htile[row][ck];
        *(short8*)(outU + (size_t)gr * 128 + ck) = val;
    }
}

// ---------------- f32 GEMM (small readout matmuls only) ----------------
#define GBM 64
#define GBN 64
#define GBK 32
__global__ __launch_bounds__(256) void gemm_f32(
    const float* __restrict__ A, const float* __restrict__ B,
    const float* __restrict__ bias, float* __restrict__ C,
    int M, int K, int Ncol)
{
    __shared__ float As[GBK][GBM + 4];
    __shared__ float Bs[GBK][GBN + 4];
    const int tx = threadIdx.x & 15;
    const int ty = threadIdx.x >> 4;
    const int row0 = blockIdx.x * GBM;
    const int col0 = blockIdx.y * GBN;
    float acc[4][4] = {};
    for (int k0 = 0; k0 < K; k0 += GBK) {
        for (int i = threadIdx.x; i < GBM * GBK; i += 256) {
            int r = i / GBK, c = i % GBK;
            float v = 0.f;
            if (row0 + r < M) v = A[(size_t)(row0 + r) * K + k0 + c];
            As[c][r] = v;
        }
        for (int i = threadIdx.x; i < GBK * GBN; i += 256) {
            int r = i / GBN, c = i % GBN;
            float v = 0.f;
            if (col0 + c < Ncol) v = B[(size_t)(k0 + r) * Ncol + col0 + c];
            Bs[r][c] = v;
        }
        __syncthreads();
        #pragma unroll
        for (int k = 0; k < GBK; ++k) {
            float a[4], b[4];
            #pragma unroll
            for (int i = 0; i < 4; ++i) a[i] = As[k][ty * 4 + i];
            #pragma unroll
            for (int j = 0; j < 4; ++j) b[j] = Bs[k][tx * 4 + j];
            #pragma unroll
            for (int i = 0; i < 4; ++i)
                #pragma unroll
                for (int j = 0; j < 4; ++j)
                    acc[i][j] = fmaf(a[i], b[j], acc[i][j]);
        }
        __syncthreads();
    }
    #pragma unroll
    for (int i = 0; i < 4; ++i) {
        int r = row0 + ty * 4 + i;
        if (r >= M) continue;
        #pragma unroll
        for (int j = 0; j < 4; ++j) {
            int c = col0 + tx * 4 + j;
            if (c >= Ncol) continue;
            C[(size_t)r * Ncol + c] = acc[i][j] + (bias ? bias[c] : 0.f);
        }
    }
}

// ---------------- weight packing ----------------
__global__ void pack_weights_bt(const float* __restrict__ attW1,
                                const float* __restrict__ mlpW,
                                const float* __restrict__ whh,
                                const float* __restrict__ attb1,
                                const float* __restrict__ mlpb,
                                const float* __restrict__ bhh,
                                bf16* __restrict__ wt, float* __restrict__ bbig)
{
    int idx = blockIdx.x * blockDim.x + threadIdx.x;
    if (idx >= 768 * 128) return;
    int j = idx >> 7, k = idx & 127;
    float v;
    if (j < 128)      v = attW1[k * 128 + j];
    else if (j < 256) v = attW1[(128 + k) * 128 + (j - 128)];
    else if (j < 384) v = mlpW[k * 128 + (j - 256)];
    else              v = whh[k * 384 + (j - 384)];
    wt[idx] = __float2bfloat16(v);
    if (k == 0) {
        float b;
        if (j < 128)      b = attb1[j];
        else if (j < 256) b = 0.f;
        else if (j < 384) b = mlpb[j - 256];
        else              b = bhh[j - 384];
        bbig[j] = b;
    }
}

// wpack[k*256 + l*4 + {0,1,2,3}] = {w1c[k][2l], w1c[k][2l+1], mlpw2[k][2l], mlpw2[k][2l+1]}
__global__ void pack_edge_w(const float* __restrict__ w1c, const float* __restrict__ wm,
                            float* __restrict__ wpack)
{
    int idx = blockIdx.x * blockDim.x + threadIdx.x;
    if (idx >= 16 * 256) return;
    int k = idx >> 8, j = idx & 255;
    int l = j >> 2, q = j & 3;
    float v = (q < 2) ? w1c[k * 128 + 2 * l + q] : wm[k * 128 + 2 * l + (q - 2)];
    wpack[idx] = v;
}

__global__ void transpose_cast(const float* __restrict__ in, bf16* __restrict__ out,
                               int K, int Ncol)
{
    int idx = blockIdx.x * blockDim.x + threadIdx.x;
    if (idx >= K * Ncol) return;
    int k = idx / Ncol, j = idx % Ncol;
    out[(size_t)j * K + k] = __float2bfloat16(in[idx]);
}

__global__ void cast_bf16_kernel(const float* __restrict__ in, bf16* __restrict__ out, int n)
{
    int idx = blockIdx.x * blockDim.x + threadIdx.x;
    if (idx < n) out[idx] = __float2bfloat16(in[idx]);
}

// ---------------- CSR build ----------------
__global__ void hist_dst_kernel(const int* __restrict__ ei, int* __restrict__ deg) {
    int e = blockIdx.x * blockDim.x + threadIdx.x;
    if (e < N_EDGES) atomicAdd(&deg[ei[N_EDGES + e]], 1);
}

__global__ __launch_bounds__(1024) void scan_local(const int* __restrict__ in,
        int* __restrict__ out, int* __restrict__ bsum, int n)
{
    __shared__ int buf[SCB];
    int i = blockIdx.x * SCB + threadIdx.x;
    int v = (i < n) ? in[i] : 0;
    buf[threadIdx.x] = v;
    __syncthreads();
    #pragma unroll
    for (int off = 1; off < SCB; off <<= 1) {
        int t = (threadIdx.x >= off) ? buf[threadIdx.x - off] : 0;
        __syncthreads();
        buf[threadIdx.x] += t;
        __syncthreads();
    }
    if (i < n) out[i] = buf[threadIdx.x] - v;
    if (threadIdx.x == SCB - 1) bsum[blockIdx.x] = buf[SCB - 1];
}
__global__ __launch_bounds__(1024) void scan_bsum(int* __restrict__ bsum, int nb,
        int* __restrict__ total_dst)
{
    __shared__ int buf[SCB];
    int v = (threadIdx.x < nb) ? bsum[threadIdx.x] : 0;
    buf[threadIdx.x] = v;
    __syncthreads();
    #pragma unroll
    for (int off = 1; off < SCB; off <<= 1) {
        int t = (threadIdx.x >= off) ? buf[threadIdx.x - off] : 0;
        __syncthreads();
        buf[threadIdx.x] += t;
        __syncthreads();
    }
    if (threadIdx.x < nb) bsum[threadIdx.x] = buf[threadIdx.x] - v;
    if (threadIdx.x == 0) *total_dst = buf[SCB - 1];
}
__global__ __launch_bounds__(1024) void scan_addoff(int* __restrict__ out,
        const int* __restrict__ bsum, int n)
{
    int i = blockIdx.x * SCB + threadIdx.x;
    if (i < n) out[i] += bsum[blockIdx.x];
}

// batch is sorted: goffs[g] = lower_bound(batch, g)
__global__ void goffs_bsearch_kernel(const int* __restrict__ batch, int* __restrict__ goffs)
{
    int g = blockIdx.x * blockDim.x + threadIdx.x;
    if (g > N_GRAPHS) return;
    int lo = 0, hi = N_NODES;
    while (lo < hi) { int mid = (lo + hi) >> 1; if (batch[mid] < g) lo = mid + 1; else hi = mid; }
    goffs[g] = lo;
}

// scatter: csrc[pos] = src; eac[pos] = ea[e]
__global__ void scatter_cse_kernel(const int* __restrict__ ei, const float* __restrict__ ea,
                                   const int* __restrict__ offs, int* __restrict__ cur,
                                   int* __restrict__ csrc, float* __restrict__ eac) {
    int e = blockIdx.x * blockDim.x + threadIdx.x;
    if (e >= N_EDGES) return;
    int d = ei[N_EDGES + e];
    int pos = offs[d] + atomicAdd(&cur[d], 1);
    csrc[pos] = ei[e];
    const float4* src = (const float4*)(ea + (size_t)e * 16);
    float4* dst = (float4*)(eac + (size_t)pos * 16);
    dst[0] = src[0]; dst[1] = src[1]; dst[2] = src[2]; dst[3] = src[3];
}

// ---------------- fused edge attention + aggregation ----------------
// one dst per wave; qm gather DOUBLE-buffered via (qu,mu) slot pairs, csrc
// 3-ahead, ea streaming 1-deep; packed f32 math; plain P|Q|M payload.
__global__ __launch_bounds__(256) void edge_fused_kernel(
    const bf16* __restrict__ pqm_b,
    const int* __restrict__ csrc, const float* __restrict__ eac,
    const float* __restrict__ wpack, const float* __restrict__ w2_g,
    const float* __restrict__ b2_g,
    const int* __restrict__ offs, bf16* __restrict__ aggrb)
{
    const unsigned short* pqm = (const unsigned short*)pqm_b;
    const int wv = threadIdx.x >> 6, lane = threadIdx.x & 63;
    const int c0 = lane * 2;
    float2v wt_[16], wm_[16];
    #pragma unroll
    for (int k = 0; k < 16; ++k) {
        float4 w = *(const float4*)(wpack + k * 256 + lane * 4);
        wt_[k] = (float2v){w.x, w.y};
        wm_[k] = (float2v){w.z, w.w};
    }
    const float w20 = w2_g[c0], w21 = w2_g[c0 + 1];
    const float b2 = b2_g[0];
    const int d = __builtin_amdgcn_readfirstlane(blockIdx.x * 4 + wv);
    if (d >= N_NODES) return;

    const ushort2 pu = *(const ushort2*)(pqm + (size_t)d * 384 + c0);
    const float2v pp = {bf2f(pu.x), bf2f(pu.y)};
    const float2v zero2 = {0.f, 0.f};
    float2v accv = zero2;
    float ssum = 0.f;
    const int b = offs[d], en = offs[d + 1];
    if (b < en) {
        const int last = en - 1;
        // prime: slot A = edge b, slot B = edge b+1, sP = src of edge b+2
        ushort2 quA, muA, quB, muB;
        int sP;
        {
            int s0 = csrc[b];
            const unsigned short* p0 = pqm + (size_t)s0 * 384;
            quA = *(const ushort2*)(p0 + 128 + c0);
            muA = *(const ushort2*)(p0 + 256 + c0);
            int s1 = csrc[min(b + 1, last)];
            const unsigned short* p1 = pqm + (size_t)s1 * 384;
            quB = *(const ushort2*)(p1 + 128 + c0);
            muB = *(const ushort2*)(p1 + 256 + c0);
            sP = csrc[min(b + 2, last)];
        }
        const float4* ep = (const float4*)(eac + (size_t)b * 16);
        float4 e0 = ep[0], e1 = ep[1], e2 = ep[2], e3 = ep[3];

        int i = b;
        #define EDGE_STEP(QU, MU)                                                  \
        {                                                                          \
            float2v tt = pp + (float2v){bf2f(QU.x), bf2f(QU.y)};                   \
            float2v mm = {bf2f(MU.x), bf2f(MU.y)};                                 \
            float er[16];                                                          \
            er[0]=e0.x; er[1]=e0.y; er[2]=e0.z; er[3]=e0.w;                        \
            er[4]=e1.x; er[5]=e1.y; er[6]=e1.z; er[7]=e1.w;                        \
            er[8]=e2.x; er[9]=e2.y; er[10]=e2.z; er[11]=e2.w;                      \
            er[12]=e3.x; er[13]=e3.y; er[14]=e3.z; er[15]=e3.w;                    \
            /* refill slot with edge i+2 (src already resident in sP) */           \
            const unsigned short* psn = pqm + (size_t)sP * 384;                    \
            QU = *(const ushort2*)(psn + 128 + c0);                                \
            MU = *(const ushort2*)(psn + 256 + c0);                                \
            sP = csrc[min(i + 3, last)];                                           \
            const float4* epn = (const float4*)(eac + (size_t)min(i + 1, last) * 16); \
            e0 = epn[0]; e1 = epn[1]; e2 = epn[2]; e3 = epn[3];                    \
            _Pragma("unroll")                                                      \
            for (int k = 0; k < 16; ++k) {                                         \
                float2v ek = {er[k], er[k]};                                       \
                tt = __builtin_elementwise_fma(ek, wt_[k], tt);                    \
                mm = __builtin_elementwise_fma(ek, wm_[k], mm);                    \
            }                                                                      \
            float2v apos = __builtin_elementwise_max(tt, zero2);                   \
            float2v aneg = __builtin_elementwise_min(tt, zero2);                   \
            float2v aa = __builtin_elementwise_fma((float2v){0.2f, 0.2f}, aneg, apos); \
            float sp = aa.x * w20 + aa.y * w21;                                    \
            _Pragma("unroll")                                                      \
            for (int off = 32; off; off >>= 1) sp += __shfl_xor(sp, off);          \
            const float ex = __expf(sp + b2);                                      \
            ssum += ex;                                                            \
            float2v mrelu = __builtin_elementwise_max(mm, zero2);                  \
            accv = __builtin_elementwise_fma((float2v){ex, ex}, mrelu, accv);      \
        }

        while (i < en) {
            EDGE_STEP(quA, muA);
            ++i;
            if (i >= en) break;
            EDGE_STEP(quB, muB);
            ++i;
        }
        #undef EDGE_STEP
    }
    const float inv = 1.f / (ssum + 1e-16f);
    bf16* outp = aggrb + (size_t)d * 128 + c0;
    outp[0] = __float2bfloat16(accv.x * inv);
    outp[1] = __float2bfloat16(accv.y * inv);
}

// ---------------- GRU elementwise (readout graph GRU only) ----------------
__global__ void gru_elem_kernel(const float* __restrict__ gi,
                                const float* __restrict__ gh,
                                const float* __restrict__ hold, float* __restrict__ hnew,
                                int rows)
{
    int idx = blockIdx.x * blockDim.x + threadIdx.x;
    if (idx >= rows * H) return;
    int r = idx >> 7, c = idx & 127;
    float ir = gi[(size_t)r * 384 + c];
    float iz = gi[(size_t)r * 384 + 128 + c];
    float in = gi[(size_t)r * 384 + 256 + c];
    float hr = gh[(size_t)r * 384 + c];
    float hz = gh[(size_t)r * 384 + 128 + c];
    float hn = gh[(size_t)r * 384 + 256 + c];
    float rg = 1.f / (1.f + __expf(-(ir + hr)));
    float zg = 1.f / (1.f + __expf(-(iz + hz)));
    float ng = tanhf(in + rg * hn);
    float hv = hold[idx];
    hnew[idx] = (1.f - zg) * ng + zg * hv;
}

// ---------------- graph pooling / readout (bf16 h) ----------------
__global__ __launch_bounds__(128) void graph_pool_sum(
    const bf16* __restrict__ hb, const int* __restrict__ goffs, float* __restrict__ g0)
{
    const unsigned short* h = (const unsigned short*)hb;
    int g = blockIdx.x, c = threadIdx.x;
    int b = goffs[g], e2 = goffs[g + 1];
    float acc = 0.f;
    for (int i = b; i < e2; ++i) acc += bf2f(h[(size_t)i * 128 + c]);
    g0[(size_t)g * 128 + c] = acc;
}

__global__ __launch_bounds__(256) void node_score2_kernel(
    const bf16* __restrict__ hW1b, const float* __restrict__ W2,
    const float* __restrict__ b2, const int* __restrict__ batch,
    float* __restrict__ es, float* __restrict__ gsum)
{
    const unsigned short* hW1 = (const unsigned short*)hW1b;
    const int wv = threadIdx.x >> 6, lane = threadIdx.x & 63;
    const int n = blockIdx.x * 4 + wv;
    if (n >= N_NODES) return;
    const int c0 = lane * 2;
    ushort2 hv = *(const ushort2*)(hW1 + (size_t)n * 128 + c0);
    float sp = tanhf(bf2f(hv.x)) * W2[c0] + tanhf(bf2f(hv.y)) * W2[c0 + 1];
    #pragma unroll
    for (int off = 32; off; off >>= 1) sp += __shfl_xor(sp, off);
    if (lane == 0) {
        float ex = __expf(sp + b2[0]);
        es[n] = ex;
        atomicAdd(&gsum[batch[n]], ex);
    }
}

__global__ __launch_bounds__(128) void graph_ctx_kernel(
    const bf16* __restrict__ hb, const int* __restrict__ goffs,
    const float* __restrict__ es, const float* __restrict__ gsum,
    float* __restrict__ ctx)
{
    const unsigned short* h = (const unsigned short*)hb;
    int g = blockIdx.x, c = threadIdx.x;
    float invs = 1.f / (gsum[g] + 1e-16f);
    int b = goffs[g], e2 = goffs[g + 1];
    float acc = 0.f;
    for (int i = b; i < e2; ++i) acc = fmaf(es[i] * invs, bf2f(h[(size_t)i * 128 + c]), acc);
    ctx[(size_t)g * 128 + c] = acc;
}

extern "C" void kernel_launch(void* const* d_in, const int* in_sizes, int n_in,
                              void* d_out, int out_size, void* d_ws, size_t ws_size,
                              hipStream_t stream) {
    const float* x      = (const float*)d_in[0];
    const int*   ei     = (const int*)d_in[1];
    const float* ea     = (const float*)d_in[2];
    const int*   batch  = (const int*)d_in[3];
    const float* embW   = (const float*)d_in[4];
    const float* embB   = (const float*)d_in[5];
    const float* attW1  = (const float*)d_in[6];
    const float* attb1  = (const float*)d_in[7];
    const float* attW2  = (const float*)d_in[8];
    const float* attb2  = (const float*)d_in[9];
    const float* mlpW   = (const float*)d_in[10];
    const float* mlpb   = (const float*)d_in[11];
    const float* gWih   = (const float*)d_in[12];
    const float* gWhh   = (const float*)d_in[13];
    const float* gbih   = (const float*)d_in[14];
    const float* gbhh   = (const float*)d_in[15];
    const float* gattW1 = (const float*)d_in[16];
    const float* gattb1 = (const float*)d_in[17];
    const float* gattW2 = (const float*)d_in[18];
    const float* gattb2 = (const float*)d_in[19];
    const float* ggWih  = (const float*)d_in[20];
    const float* ggWhh  = (const float*)d_in[21];
    const float* ggbih  = (const float*)d_in[22];
    const float* ggbhh  = (const float*)d_in[23];
    float* out = (float*)d_out;

    void* basep = nullptr;
    (void)hipGetSymbolAddress(&basep, HIP_SYMBOL(g_afp_ws));
    char* base = (char*)basep;
    bf16*  h0b   = (bf16*)(base + OFF_H0B);
    bf16*  h1b   = (bf16*)(base + OFF_H1B);
    bf16*  xb    = (bf16*)(base + OFF_XB);
    bf16*  pqmb  = (bf16*)(base + OFF_PQMB);
    bf16*  ghx   = (bf16*)(base + OFF_GHX);
    bf16*  hW1b  = (bf16*)(base + OFF_HW1B);
    bf16*  aggrb = (bf16*)(base + OFF_AGB);
    float* es    = (float*)(base + OFF_ES);
    bf16*  wt    = (bf16*)(base + OFF_WT);
    bf16*  wiht  = (bf16*)(base + OFF_WIHT);
    bf16*  embt  = (bf16*)(base + OFF_EMBT);
    float* wpack = (float*)(base + OFF_WPK);
    float* bbig  = (float*)(base + OFF_BBIG);
    float* g0b   = (float*)(base + OFF_G0);
    float* gAb   = (float*)(base + OFF_GA);
    float* ctx   = (float*)(base + OFF_CTX);
    float* gictx = (float*)(base + OFF_GICTX);
    float* ghr   = (float*)(base + OFF_GHR);
    int*   deg   = (int*)(base + OFF_DEG);
    int*   cur   = (int*)(base + OFF_CUR);
    float* gsum  = (float*)(base + OFF_GSUM);
    int*   offs  = (int*)(base + OFF_OFFS);
    int*   goffs = (int*)(base + OFF_GOFFS);
    int*   csrc  = (int*)(base + OFF_CSRC);
    float* eac   = (float*)(base + OFF_EAC);
    int*   bsum  = (int*)(base + OFF_BSUM);

    (void)hipMemsetAsync(deg, 0, SZ_ZERO, stream);   // deg, cur, gsum

    const int nbN = (N_NODES + SCB - 1) / SCB;

    hist_dst_kernel<<<(N_EDGES + 255) / 256, 256, 0, stream>>>(ei, deg);
    scan_local<<<nbN, SCB, 0, stream>>>(deg, offs, bsum, N_NODES);
    scan_bsum<<<1, SCB, 0, stream>>>(bsum, nbN, offs + N_NODES);
    scan_addoff<<<nbN, SCB, 0, stream>>>(offs, bsum, N_NODES);
    scatter_cse_kernel<<<(N_EDGES + 255) / 256, 256, 0, stream>>>(ei, ea, offs, cur, csrc, eac);
    goffs_bsearch_kernel<<<(N_GRAPHS + 256) / 256, 256, 0, stream>>>(batch, goffs);

    cast_bf16_kernel<<<(N_NODES * FN + 255) / 256, 256, 0, stream>>>(x, xb, N_NODES * FN);
    transpose_cast<<<(FN * 128 + 255) / 256, 256, 0, stream>>>(embW, embt, FN, 128);

    {
        dim3 g((N_NODES + 63) / 64, 128 / 64);
        gemm_mfma<64><<<g, 256, 0, stream>>>(xb, embt, embB, h0b, nullptr,
                                             N_NODES, 128, 1 | 8);
    }

    bf16* hcurb = h0b;
    bf16* hnextb = h1b;
    for (int l = 0; l < NL; ++l) {
        pack_weights_bt<<<(768 * 128 + 255) / 256, 256, 0, stream>>>(
            attW1 + (size_t)l * 272 * 128, mlpW + (size_t)l * 144 * 128,
            gWhh + (size_t)l * 128 * 384, attb1 + l * 128, mlpb + l * 128,
            gbhh + l * 384, wt, bbig);
        pack_edge_w<<<16, 256, 0, stream>>>(
            attW1 + (size_t)l * 272 * 128 + 256 * 128,
            mlpW + (size_t)l * 144 * 128 + 128 * 128, wpack);
        {
            dim3 g((N_NODES + 63) / 64, 768 / 64);
            gemm_mfma<128><<<g, 256, 0, stream>>>(hcurb, wt, bbig, pqmb, ghx,
                                                  N_NODES, 768, 2);
        }
        edge_fused_kernel<<<(N_NODES + 3) / 4, 256, 0, stream>>>(
            pqmb, csrc, eac, wpack, attW2 + (size_t)l * 128, attb2 + l,
            offs, aggrb);
        transpose_cast<<<(128 * 384 + 255) / 256, 256, 0, stream>>>(
            gWih + (size_t)l * 128 * 384, wiht, 128, 384);
        gemm_gru<<<(N_NODES + 63) / 64, 256, 0, stream>>>(
            aggrb, wiht, gbih + l * 384, ghx, hcurb, hnextb, N_NODES);
        bf16* tb = hcurb; hcurb = hnextb; hnextb = tb;
    }

    // readout (h fixed across T -> ctx computed once)
    graph_pool_sum<<<N_GRAPHS, 128, 0, stream>>>(hcurb, goffs, g0b);
    transpose_cast<<<(128 * 128 + 255) / 256, 256, 0, stream>>>(gattW1, wiht, 128, 128);
    {
        dim3 g((N_NODES + 63) / 64, 128 / 64);
        gemm_mfma<128><<<g, 256, 0, stream>>>(hcurb, wiht, gattb1, hW1b, nullptr,
                                              N_NODES, 128, 8);
    }
    node_score2_kernel<<<(N_NODES + 3) / 4, 256, 0, stream>>>(
        hW1b, gattW2, gattb2, batch, es, gsum);
    graph_ctx_kernel<<<N_GRAPHS, 128, 0, stream>>>(hcurb, goffs, es, gsum, ctx);

    dim3 gg((N_GRAPHS + 63) / 64, 384 / 64);
    gemm_f32<<<gg, 256, 0, stream>>>(ctx, ggWih, ggbih, gictx, N_GRAPHS, H, 384);
    gemm_f32<<<gg, 256, 0, stream>>>(g0b, ggWhh, ggbhh, ghr, N_GRAPHS, H, 384);
    gru_elem_kernel<<<((size_t)N_GRAPHS * H + 255) / 256, 256, 0, stream>>>(
        gictx, ghr, g0b, gAb, N_GRAPHS);
    gemm_f32<<<gg, 256, 0, stream>>>(gAb, ggWhh, ggbhh, ghr, N_GRAPHS, H, 384);
    gru_elem_kernel<<<((size_t)N_GRAPHS * H + 255) / 256, 256, 0, stream>>>(
        gictx, ghr, gAb, out, N_GRAPHS);
}

// Round 18
// 755.345 us; speedup vs baseline: 1.0799x; 1.0799x over previous
//
#include <hip/hip_runtime.h>
#include <hip/hip_bf16.h>
#include <math.h>

#define N_NODES 50000
#define N_EDGES 640000
#define N_GRAPHS 2000
#define FN 64
#define FE 16
#define H 128
#define NL 2
#define SCB 1024

typedef __attribute__((ext_vector_type(8))) short short8;
typedef __attribute__((ext_vector_type(4))) float float4v;
typedef __attribute__((ext_vector_type(2))) float float2v;
typedef __hip_bfloat16 bf16;

// ---------------- static workspace ----------------
static constexpr size_t AL = 256;
static constexpr size_t alup(size_t x) { return (x + AL - 1) & ~(AL - 1); }

static constexpr size_t SZ_HB    = (size_t)N_NODES * H * 2;
static constexpr size_t SZ_XB    = (size_t)N_NODES * FN * 2;
static constexpr size_t SZ_PQMB  = (size_t)N_NODES * 384 * 2;
static constexpr size_t SZ_GHX   = (size_t)N_NODES * 384 * 2;
static constexpr size_t SZ_HW1B  = (size_t)N_NODES * H * 2;
static constexpr size_t SZ_AGB   = (size_t)N_NODES * H * 2;
static constexpr size_t SZ_NF    = (size_t)N_NODES * 4;
static constexpr size_t SZ_WT    = (size_t)768 * 128 * 2;
static constexpr size_t SZ_WIHT  = (size_t)384 * 128 * 2;
static constexpr size_t SZ_EMBT  = (size_t)128 * 64 * 2;
static constexpr size_t SZ_WPK   = (size_t)16 * 256 * 4;
static constexpr size_t SZ_BBIG  = (size_t)768 * 4;
static constexpr size_t SZ_G128  = (size_t)N_GRAPHS * 128 * 4;
static constexpr size_t SZ_G384  = (size_t)N_GRAPHS * 384 * 4;
static constexpr size_t SZ_GF    = (size_t)N_GRAPHS * 4;
static constexpr size_t SZ_CSRC  = (size_t)N_EDGES * 4 + 64;
static constexpr size_t SZ_EAC   = (size_t)N_EDGES * 64 + 64;
static constexpr size_t SZ_BSUM  = 256 * 4;

static constexpr size_t OFF_H0B   = 0;
static constexpr size_t OFF_H1B   = alup(OFF_H0B + SZ_HB);
static constexpr size_t OFF_XB    = alup(OFF_H1B + SZ_HB);
static constexpr size_t OFF_PQMB  = alup(OFF_XB + SZ_XB);
static constexpr size_t OFF_GHX   = alup(OFF_PQMB + SZ_PQMB);
static constexpr size_t OFF_HW1B  = alup(OFF_GHX + SZ_GHX);
static constexpr size_t OFF_AGB   = alup(OFF_HW1B + SZ_HW1B);
static constexpr size_t OFF_ES    = alup(OFF_AGB + SZ_AGB);
static constexpr size_t OFF_WT    = alup(OFF_ES + SZ_NF);
static constexpr size_t OFF_WIHT  = alup(OFF_WT + SZ_WT);
static constexpr size_t OFF_EMBT  = alup(OFF_WIHT + SZ_WIHT);
static constexpr size_t OFF_WPK   = alup(OFF_EMBT + SZ_EMBT);
static constexpr size_t OFF_BBIG  = alup(OFF_WPK + SZ_WPK);
static constexpr size_t OFF_G0    = alup(OFF_BBIG + SZ_BBIG);
static constexpr size_t OFF_GA    = alup(OFF_G0 + SZ_G128);
static constexpr size_t OFF_CTX   = alup(OFF_GA + SZ_G128);
static constexpr size_t OFF_GICTX = alup(OFF_CTX + SZ_G128);
static constexpr size_t OFF_GHR   = alup(OFF_GICTX + SZ_G384);
static constexpr size_t OFF_DEG   = alup(OFF_GHR + SZ_G384);
static constexpr size_t OFF_CUR   = alup(OFF_DEG + SZ_NF);
static constexpr size_t OFF_GSUM  = alup(OFF_CUR + SZ_NF);
static constexpr size_t SZ_ZERO   = OFF_GSUM + SZ_GF - OFF_DEG;
static constexpr size_t OFF_OFFS  = alup(OFF_GSUM + SZ_GF);
static constexpr size_t OFF_GOFFS = alup(OFF_OFFS + SZ_NF + 4);
static constexpr size_t OFF_CSRC  = alup(OFF_GOFFS + SZ_GF + 4);
static constexpr size_t OFF_EAC   = alup(OFF_CSRC + SZ_CSRC);
static constexpr size_t OFF_BSUM  = alup(OFF_EAC + SZ_EAC);
static constexpr size_t TOTAL_WS  = alup(OFF_BSUM + SZ_BSUM);

__device__ unsigned char g_afp_ws[TOTAL_WS];

__device__ inline float bf2f(unsigned short u) {
    unsigned int x = ((unsigned int)u) << 16;
    return __uint_as_float(x);
}
__device__ inline unsigned short f2bfu(float f) {
    bf16 b = __float2bfloat16(f);
    return *(unsigned short*)&b;
}

// ------- 128x128-tile MFMA bf16 GEMM (4 waves x 64x64 sub-tile, 4x4 frags) -------
// mode bit0: relu. bit1: split768 (col tiles align: 0/128/256 -> Cb, 384/512/640 -> Cb2,
// both stride 384). bit3: plain bf16 Cb stride Ncol.
template<int K>
__global__ __launch_bounds__(256) void gemm_mfma_big(
    const bf16* __restrict__ Abf, const bf16* __restrict__ Btbf,
    const float* __restrict__ bias,
    bf16* __restrict__ Cb, bf16* __restrict__ Cb2,
    int M, int Ncol, int mode)
{
    __shared__ unsigned short ctile[128][136];
    const unsigned short* A  = (const unsigned short*)Abf;
    const unsigned short* Bt = (const unsigned short*)Btbf;
    const int l  = threadIdx.x & 63;
    const int w  = threadIdx.x >> 6;
    const int wm = w >> 1, wn = w & 1;
    const int rowb = blockIdx.x * 128;
    const int row0 = rowb + wm * 64;
    const int col0 = blockIdx.y * 128 + wn * 64;
    const int lr = l & 15;
    const int lk = (l >> 4) * 8;
    float4v acc[4][4] = {};
    #pragma unroll
    for (int k0 = 0; k0 < K; k0 += 32) {
        short8 a[4], b[4];
        #pragma unroll
        for (int i = 0; i < 4; ++i) {
            int r = row0 + i * 16 + lr;
            if (r >= M) r = M - 1;
            a[i] = *(const short8*)(A + (size_t)r * K + k0 + lk);
        }
        #pragma unroll
        for (int j = 0; j < 4; ++j) {
            int c = col0 + j * 16 + lr;
            b[j] = *(const short8*)(Bt + (size_t)c * K + k0 + lk);
        }
        #pragma unroll
        for (int i = 0; i < 4; ++i)
            #pragma unroll
            for (int j = 0; j < 4; ++j)
                acc[i][j] = __builtin_amdgcn_mfma_f32_16x16x32_bf16(a[i], b[j], acc[i][j], 0, 0, 0);
    }
    const int orow = (l >> 4) * 4;
    const int ocol = l & 15;
    #pragma unroll
    for (int i = 0; i < 4; ++i) {
        #pragma unroll
        for (int j = 0; j < 4; ++j) {
            const int lc = wn * 64 + j * 16 + ocol;
            const int gc = blockIdx.y * 128 + lc;
            const float bi = bias ? bias[gc] : 0.f;
            #pragma unroll
            for (int r = 0; r < 4; ++r) {
                const int lrow = wm * 64 + i * 16 + orow + r;
                float v = acc[i][j][r] + bi;
                if (mode & 1) v = fmaxf(v, 0.f);
                ctile[lrow][lc] = f2bfu(v);
            }
        }
    }
    __syncthreads();
    unsigned short* CbU  = (unsigned short*)Cb;
    unsigned short* Cb2U = (unsigned short*)Cb2;
    for (int u = threadIdx.x; u < 2048; u += 256) {
        const int row = u >> 4, ck = (u & 15) * 8;
        const int gr = rowb + row;
        if (gr >= M) continue;
        short8 val = *(const short8*)&ctile[row][ck];
        const int gc = blockIdx.y * 128 + ck;
        if (mode & 2) {
            if (gc < 384) *(short8*)(CbU + (size_t)gr * 384 + gc) = val;
            else          *(short8*)(Cb2U + (size_t)gr * 384 + (gc - 384)) = val;
        } else {
            *(short8*)(CbU + (size_t)gr * Ncol + gc) = val;
        }
    }
}

// ---------------- fused gi-GEMM + GRU (bf16 h), LDS-staged stores ----------------
__global__ __launch_bounds__(256) void gemm_gru(
    const bf16* __restrict__ Abf, const bf16* __restrict__ Btbf,
    const float* __restrict__ bias, const bf16* __restrict__ ghb,
    const bf16* __restrict__ holdb, bf16* __restrict__ hnewb, int M)
{
    __shared__ unsigned short htile[64][136];
    const unsigned short* A  = (const unsigned short*)Abf;
    const unsigned short* Bt = (const unsigned short*)Btbf;
    const unsigned short* gh = (const unsigned short*)ghb;
    const unsigned short* hold = (const unsigned short*)holdb;
    const int l  = threadIdx.x & 63;
    const int w  = threadIdx.x >> 6;
    const int rowb = blockIdx.x * 64;
    const int row0 = rowb + w * 16;
    const int lr = l & 15;
    const int lk = (l >> 4) * 8;
    float4v acc[24] = {};
    #pragma unroll
    for (int k0 = 0; k0 < 128; k0 += 32) {
        int r = row0 + lr;
        if (r >= M) r = M - 1;
        short8 a = *(const short8*)(A + (size_t)r * 128 + k0 + lk);
        #pragma unroll
        for (int j = 0; j < 24; ++j) {
            short8 b = *(const short8*)(Bt + (size_t)(j * 16 + lr) * 128 + k0 + lk);
            acc[j] = __builtin_amdgcn_mfma_f32_16x16x32_bf16(a, b, acc[j], 0, 0, 0);
        }
    }
    const int orow = (l >> 4) * 4;
    const int ocol = l & 15;
    #pragma unroll
    for (int a_ = 0; a_ < 8; ++a_) {
        const int c = a_ * 16 + ocol;
        const float bir = bias[c], biz = bias[c + 128], bin = bias[c + 256];
        #pragma unroll
        for (int r = 0; r < 4; ++r) {
            const int gr = row0 + orow + r;
            const int grc = (gr >= M) ? (M - 1) : gr;
            float ir = acc[a_][r] + bir;
            float iz = acc[a_ + 8][r] + biz;
            float in = acc[a_ + 16][r] + bin;
            const unsigned short* ghp = gh + (size_t)grc * 384;
            float hr = bf2f(ghp[c]);
            float hz = bf2f(ghp[128 + c]);
            float hn = bf2f(ghp[256 + c]);
            float rg = 1.f / (1.f + __expf(-(ir + hr)));
            float zg = 1.f / (1.f + __expf(-(iz + hz)));
            float ng = tanhf(in + rg * hn);
            float hv = bf2f(hold[(size_t)grc * 128 + c]);
            float o = (1.f - zg) * ng + zg * hv;
            htile[w * 16 + orow + r][c] = f2bfu(o);
        }
    }
    __syncthreads();
    unsigned short* outU = (unsigned short*)hnewb;
    for (int u = threadIdx.x; u < 1024; u += 256) {
        const int row = u >> 4, ck = (u & 15) * 8;
        const int gr = rowb + row;
        if (gr >= M) continue;
        short8 val = *(const short8*)&htile[row][ck];
        *(short8*)(outU + (size_t)gr * 128 + ck) = val;
    }
}

// ---------------- f32 GEMM (small readout matmuls only) ----------------
#define GBM 64
#define GBN 64
#define GBK 32
__global__ __launch_bounds__(256) void gemm_f32(
    const float* __restrict__ A, const float* __restrict__ B,
    const float* __restrict__ bias, float* __restrict__ C,
    int M, int K, int Ncol)
{
    __shared__ float As[GBK][GBM + 4];
    __shared__ float Bs[GBK][GBN + 4];
    const int tx = threadIdx.x & 15;
    const int ty = threadIdx.x >> 4;
    const int row0 = blockIdx.x * GBM;
    const int col0 = blockIdx.y * GBN;
    float acc[4][4] = {};
    for (int k0 = 0; k0 < K; k0 += GBK) {
        for (int i = threadIdx.x; i < GBM * GBK; i += 256) {
            int r = i / GBK, c = i % GBK;
            float v = 0.f;
            if (row0 + r < M) v = A[(size_t)(row0 + r) * K + k0 + c];
            As[c][r] = v;
        }
        for (int i = threadIdx.x; i < GBK * GBN; i += 256) {
            int r = i / GBN, c = i % GBN;
            float v = 0.f;
            if (col0 + c < Ncol) v = B[(size_t)(k0 + r) * Ncol + col0 + c];
            Bs[r][c] = v;
        }
        __syncthreads();
        #pragma unroll
        for (int k = 0; k < GBK; ++k) {
            float a[4], b[4];
            #pragma unroll
            for (int i = 0; i < 4; ++i) a[i] = As[k][ty * 4 + i];
            #pragma unroll
            for (int j = 0; j < 4; ++j) b[j] = Bs[k][tx * 4 + j];
            #pragma unroll
            for (int i = 0; i < 4; ++i)
                #pragma unroll
                for (int j = 0; j < 4; ++j)
                    acc[i][j] = fmaf(a[i], b[j], acc[i][j]);
        }
        __syncthreads();
    }
    #pragma unroll
    for (int i = 0; i < 4; ++i) {
        int r = row0 + ty * 4 + i;
        if (r >= M) continue;
        #pragma unroll
        for (int j = 0; j < 4; ++j) {
            int c = col0 + tx * 4 + j;
            if (c >= Ncol) continue;
            C[(size_t)r * Ncol + c] = acc[i][j] + (bias ? bias[c] : 0.f);
        }
    }
}

// ---------------- weight packing ----------------
__global__ void pack_weights_bt(const float* __restrict__ attW1,
                                const float* __restrict__ mlpW,
                                const float* __restrict__ whh,
                                const float* __restrict__ attb1,
                                const float* __restrict__ mlpb,
                                const float* __restrict__ bhh,
                                bf16* __restrict__ wt, float* __restrict__ bbig)
{
    int idx = blockIdx.x * blockDim.x + threadIdx.x;
    if (idx >= 768 * 128) return;
    int j = idx >> 7, k = idx & 127;
    float v;
    if (j < 128)      v = attW1[k * 128 + j];
    else if (j < 256) v = attW1[(128 + k) * 128 + (j - 128)];
    else if (j < 384) v = mlpW[k * 128 + (j - 256)];
    else              v = whh[k * 384 + (j - 384)];
    wt[idx] = __float2bfloat16(v);
    if (k == 0) {
        float b;
        if (j < 128)      b = attb1[j];
        else if (j < 256) b = 0.f;
        else if (j < 384) b = mlpb[j - 256];
        else              b = bhh[j - 384];
        bbig[j] = b;
    }
}

// wpack[k*256 + l*4 + {0,1,2,3}] = {w1c[k][2l], w1c[k][2l+1], mlpw2[k][2l], mlpw2[k][2l+1]}
__global__ void pack_edge_w(const float* __restrict__ w1c, const float* __restrict__ wm,
                            float* __restrict__ wpack)
{
    int idx = blockIdx.x * blockDim.x + threadIdx.x;
    if (idx >= 16 * 256) return;
    int k = idx >> 8, j = idx & 255;
    int l = j >> 2, q = j & 3;
    float v = (q < 2) ? w1c[k * 128 + 2 * l + q] : wm[k * 128 + 2 * l + (q - 2)];
    wpack[idx] = v;
}

__global__ void transpose_cast(const float* __restrict__ in, bf16* __restrict__ out,
                               int K, int Ncol)
{
    int idx = blockIdx.x * blockDim.x + threadIdx.x;
    if (idx >= K * Ncol) return;
    int k = idx / Ncol, j = idx % Ncol;
    out[(size_t)j * K + k] = __float2bfloat16(in[idx]);
}

__global__ void cast_bf16_kernel(const float* __restrict__ in, bf16* __restrict__ out, int n)
{
    int idx = blockIdx.x * blockDim.x + threadIdx.x;
    if (idx < n) out[idx] = __float2bfloat16(in[idx]);
}

// ---------------- CSR build ----------------
__global__ void hist_dst_kernel(const int* __restrict__ ei, int* __restrict__ deg) {
    int e = blockIdx.x * blockDim.x + threadIdx.x;
    if (e < N_EDGES) atomicAdd(&deg[ei[N_EDGES + e]], 1);
}

__global__ __launch_bounds__(1024) void scan_local(const int* __restrict__ in,
        int* __restrict__ out, int* __restrict__ bsum, int n)
{
    __shared__ int buf[SCB];
    int i = blockIdx.x * SCB + threadIdx.x;
    int v = (i < n) ? in[i] : 0;
    buf[threadIdx.x] = v;
    __syncthreads();
    #pragma unroll
    for (int off = 1; off < SCB; off <<= 1) {
        int t = (threadIdx.x >= off) ? buf[threadIdx.x - off] : 0;
        __syncthreads();
        buf[threadIdx.x] += t;
        __syncthreads();
    }
    if (i < n) out[i] = buf[threadIdx.x] - v;
    if (threadIdx.x == SCB - 1) bsum[blockIdx.x] = buf[SCB - 1];
}
__global__ __launch_bounds__(1024) void scan_bsum(int* __restrict__ bsum, int nb,
        int* __restrict__ total_dst)
{
    __shared__ int buf[SCB];
    int v = (threadIdx.x < nb) ? bsum[threadIdx.x] : 0;
    buf[threadIdx.x] = v;
    __syncthreads();
    #pragma unroll
    for (int off = 1; off < SCB; off <<= 1) {
        int t = (threadIdx.x >= off) ? buf[threadIdx.x - off] : 0;
        __syncthreads();
        buf[threadIdx.x] += t;
        __syncthreads();
    }
    if (threadIdx.x < nb) bsum[threadIdx.x] = buf[threadIdx.x] - v;
    if (threadIdx.x == 0) *total_dst = buf[SCB - 1];
}
__global__ __launch_bounds__(1024) void scan_addoff(int* __restrict__ out,
        const int* __restrict__ bsum, int n)
{
    int i = blockIdx.x * SCB + threadIdx.x;
    if (i < n) out[i] += bsum[blockIdx.x];
}

// batch is sorted: goffs[g] = lower_bound(batch, g)
__global__ void goffs_bsearch_kernel(const int* __restrict__ batch, int* __restrict__ goffs)
{
    int g = blockIdx.x * blockDim.x + threadIdx.x;
    if (g > N_GRAPHS) return;
    int lo = 0, hi = N_NODES;
    while (lo < hi) { int mid = (lo + hi) >> 1; if (batch[mid] < g) lo = mid + 1; else hi = mid; }
    goffs[g] = lo;
}

// scatter: csrc[pos] = src; eac[pos] = ea[e]
__global__ void scatter_cse_kernel(const int* __restrict__ ei, const float* __restrict__ ea,
                                   const int* __restrict__ offs, int* __restrict__ cur,
                                   int* __restrict__ csrc, float* __restrict__ eac) {
    int e = blockIdx.x * blockDim.x + threadIdx.x;
    if (e >= N_EDGES) return;
    int d = ei[N_EDGES + e];
    int pos = offs[d] + atomicAdd(&cur[d], 1);
    csrc[pos] = ei[e];
    const float4* src = (const float4*)(ea + (size_t)e * 16);
    float4* dst = (float4*)(eac + (size_t)pos * 16);
    dst[0] = src[0]; dst[1] = src[1]; dst[2] = src[2]; dst[3] = src[3];
}

// ---------------- fused edge attention + aggregation (r15 exact) ----------------
// one dst per wave; csrc 2-ahead prefetch; packed f32 math; plain P|Q|M payload.
__global__ __launch_bounds__(256) void edge_fused_kernel(
    const bf16* __restrict__ pqm_b,
    const int* __restrict__ csrc, const float* __restrict__ eac,
    const float* __restrict__ wpack, const float* __restrict__ w2_g,
    const float* __restrict__ b2_g,
    const int* __restrict__ offs, bf16* __restrict__ aggrb)
{
    const unsigned short* pqm = (const unsigned short*)pqm_b;
    const int wv = threadIdx.x >> 6, lane = threadIdx.x & 63;
    const int c0 = lane * 2;
    float2v wt_[16], wm_[16];
    #pragma unroll
    for (int k = 0; k < 16; ++k) {
        float4 w = *(const float4*)(wpack + k * 256 + lane * 4);
        wt_[k] = (float2v){w.x, w.y};
        wm_[k] = (float2v){w.z, w.w};
    }
    const float w20 = w2_g[c0], w21 = w2_g[c0 + 1];
    const float b2 = b2_g[0];
    const int d = __builtin_amdgcn_readfirstlane(blockIdx.x * 4 + wv);
    if (d >= N_NODES) return;

    const ushort2 pu = *(const ushort2*)(pqm + (size_t)d * 384 + c0);
    const float2v pp = {bf2f(pu.x), bf2f(pu.y)};
    const float2v zero2 = {0.f, 0.f};
    float2v accv = zero2;
    float ssum = 0.f;
    const int b = offs[d], en = offs[d + 1];
    if (b < en) {
        const int last = en - 1;
        int sN = csrc[b];
        int sN2 = csrc[min(b + 1, last)];
        const unsigned short* ps0 = pqm + (size_t)sN * 384;
        ushort2 qu = *(const ushort2*)(ps0 + 128 + c0);
        ushort2 mu = *(const ushort2*)(ps0 + 256 + c0);
        const float4* ep = (const float4*)(eac + (size_t)b * 16);
        float4 e0 = ep[0], e1 = ep[1], e2 = ep[2], e3 = ep[3];
        for (int i = b; i < en; ++i) {
            float2v tt = pp + (float2v){bf2f(qu.x), bf2f(qu.y)};
            float2v mm = {bf2f(mu.x), bf2f(mu.y)};
            float er[16];
            er[0]=e0.x; er[1]=e0.y; er[2]=e0.z; er[3]=e0.w;
            er[4]=e1.x; er[5]=e1.y; er[6]=e1.z; er[7]=e1.w;
            er[8]=e2.x; er[9]=e2.y; er[10]=e2.z; er[11]=e2.w;
            er[12]=e3.x; er[13]=e3.y; er[14]=e3.z; er[15]=e3.w;
            if (i + 1 < en) {
                const unsigned short* psn = pqm + (size_t)sN2 * 384;
                qu = *(const ushort2*)(psn + 128 + c0);
                mu = *(const ushort2*)(psn + 256 + c0);
                const float4* epn = (const float4*)(eac + (size_t)(i + 1) * 16);
                e0 = epn[0]; e1 = epn[1]; e2 = epn[2]; e3 = epn[3];
                sN2 = csrc[min(i + 2, last)];
            }
            #pragma unroll
            for (int k = 0; k < 16; ++k) {
                float2v ek = {er[k], er[k]};
                tt = __builtin_elementwise_fma(ek, wt_[k], tt);
                mm = __builtin_elementwise_fma(ek, wm_[k], mm);
            }
            float2v apos = __builtin_elementwise_max(tt, zero2);
            float2v aneg = __builtin_elementwise_min(tt, zero2);
            float2v aa = __builtin_elementwise_fma((float2v){0.2f, 0.2f}, aneg, apos);
            float sp = aa.x * w20 + aa.y * w21;
            #pragma unroll
            for (int off = 32; off; off >>= 1) sp += __shfl_xor(sp, off);
            const float ex = __expf(sp + b2);
            ssum += ex;
            float2v mrelu = __builtin_elementwise_max(mm, zero2);
            accv = __builtin_elementwise_fma((float2v){ex, ex}, mrelu, accv);
        }
    }
    const float inv = 1.f / (ssum + 1e-16f);
    bf16* outp = aggrb + (size_t)d * 128 + c0;
    outp[0] = __float2bfloat16(accv.x * inv);
    outp[1] = __float2bfloat16(accv.y * inv);
}

// ---------------- GRU elementwise (readout graph GRU only) ----------------
__global__ void gru_elem_kernel(const float* __restrict__ gi,
                                const float* __restrict__ gh,
                                const float* __restrict__ hold, float* __restrict__ hnew,
                                int rows)
{
    int idx = blockIdx.x * blockDim.x + threadIdx.x;
    if (idx >= rows * H) return;
    int r = idx >> 7, c = idx & 127;
    float ir = gi[(size_t)r * 384 + c];
    float iz = gi[(size_t)r * 384 + 128 + c];
    float in = gi[(size_t)r * 384 + 256 + c];
    float hr = gh[(size_t)r * 384 + c];
    float hz = gh[(size_t)r * 384 + 128 + c];
    float hn = gh[(size_t)r * 384 + 256 + c];
    float rg = 1.f / (1.f + __expf(-(ir + hr)));
    float zg = 1.f / (1.f + __expf(-(iz + hz)));
    float ng = tanhf(in + rg * hn);
    float hv = hold[idx];
    hnew[idx] = (1.f - zg) * ng + zg * hv;
}

// ---------------- graph pooling / readout (bf16 h) ----------------
__global__ __launch_bounds__(128) void graph_pool_sum(
    const bf16* __restrict__ hb, const int* __restrict__ goffs, float* __restrict__ g0)
{
    const unsigned short* h = (const unsigned short*)hb;
    int g = blockIdx.x, c = threadIdx.x;
    int b = goffs[g], e2 = goffs[g + 1];
    float acc = 0.f;
    for (int i = b; i < e2; ++i) acc += bf2f(h[(size_t)i * 128 + c]);
    g0[(size_t)g * 128 + c] = acc;
}

__global__ __launch_bounds__(256) void node_score2_kernel(
    const bf16* __restrict__ hW1b, const float* __restrict__ W2,
    const float* __restrict__ b2, const int* __restrict__ batch,
    float* __restrict__ es, float* __restrict__ gsum)
{
    const unsigned short* hW1 = (const unsigned short*)hW1b;
    const int wv = threadIdx.x >> 6, lane = threadIdx.x & 63;
    const int n = blockIdx.x * 4 + wv;
    if (n >= N_NODES) return;
    const int c0 = lane * 2;
    ushort2 hv = *(const ushort2*)(hW1 + (size_t)n * 128 + c0);
    float sp = tanhf(bf2f(hv.x)) * W2[c0] + tanhf(bf2f(hv.y)) * W2[c0 + 1];
    #pragma unroll
    for (int off = 32; off; off >>= 1) sp += __shfl_xor(sp, off);
    if (lane == 0) {
        float ex = __expf(sp + b2[0]);
        es[n] = ex;
        atomicAdd(&gsum[batch[n]], ex);
    }
}

__global__ __launch_bounds__(128) void graph_ctx_kernel(
    const bf16* __restrict__ hb, const int* __restrict__ goffs,
    const float* __restrict__ es, const float* __restrict__ gsum,
    float* __restrict__ ctx)
{
    const unsigned short* h = (const unsigned short*)hb;
    int g = blockIdx.x, c = threadIdx.x;
    float invs = 1.f / (gsum[g] + 1e-16f);
    int b = goffs[g], e2 = goffs[g + 1];
    float acc = 0.f;
    for (int i = b; i < e2; ++i) acc = fmaf(es[i] * invs, bf2f(h[(size_t)i * 128 + c]), acc);
    ctx[(size_t)g * 128 + c] = acc;
}

extern "C" void kernel_launch(void* const* d_in, const int* in_sizes, int n_in,
                              void* d_out, int out_size, void* d_ws, size_t ws_size,
                              hipStream_t stream) {
    const float* x      = (const float*)d_in[0];
    const int*   ei     = (const int*)d_in[1];
    const float* ea     = (const float*)d_in[2];
    const int*   batch  = (const int*)d_in[3];
    const float* embW   = (const float*)d_in[4];
    const float* embB   = (const float*)d_in[5];
    const float* attW1  = (const float*)d_in[6];
    const float* attb1  = (const float*)d_in[7];
    const float* attW2  = (const float*)d_in[8];
    const float* attb2  = (const float*)d_in[9];
    const float* mlpW   = (const float*)d_in[10];
    const float* mlpb   = (const float*)d_in[11];
    const float* gWih   = (const float*)d_in[12];
    const float* gWhh   = (const float*)d_in[13];
    const float* gbih   = (const float*)d_in[14];
    const float* gbhh   = (const float*)d_in[15];
    const float* gattW1 = (const float*)d_in[16];
    const float* gattb1 = (const float*)d_in[17];
    const float* gattW2 = (const float*)d_in[18];
    const float* gattb2 = (const float*)d_in[19];
    const float* ggWih  = (const float*)d_in[20];
    const float* ggWhh  = (const float*)d_in[21];
    const float* ggbih  = (const float*)d_in[22];
    const float* ggbhh  = (const float*)d_in[23];
    float* out = (float*)d_out;

    void* basep = nullptr;
    (void)hipGetSymbolAddress(&basep, HIP_SYMBOL(g_afp_ws));
    char* base = (char*)basep;
    bf16*  h0b   = (bf16*)(base + OFF_H0B);
    bf16*  h1b   = (bf16*)(base + OFF_H1B);
    bf16*  xb    = (bf16*)(base + OFF_XB);
    bf16*  pqmb  = (bf16*)(base + OFF_PQMB);
    bf16*  ghx   = (bf16*)(base + OFF_GHX);
    bf16*  hW1b  = (bf16*)(base + OFF_HW1B);
    bf16*  aggrb = (bf16*)(base + OFF_AGB);
    float* es    = (float*)(base + OFF_ES);
    bf16*  wt    = (bf16*)(base + OFF_WT);
    bf16*  wiht  = (bf16*)(base + OFF_WIHT);
    bf16*  embt  = (bf16*)(base + OFF_EMBT);
    float* wpack = (float*)(base + OFF_WPK);
    float* bbig  = (float*)(base + OFF_BBIG);
    float* g0b   = (float*)(base + OFF_G0);
    float* gAb   = (float*)(base + OFF_GA);
    float* ctx   = (float*)(base + OFF_CTX);
    float* gictx = (float*)(base + OFF_GICTX);
    float* ghr   = (float*)(base + OFF_GHR);
    int*   deg   = (int*)(base + OFF_DEG);
    int*   cur   = (int*)(base + OFF_CUR);
    float* gsum  = (float*)(base + OFF_GSUM);
    int*   offs  = (int*)(base + OFF_OFFS);
    int*   goffs = (int*)(base + OFF_GOFFS);
    int*   csrc  = (int*)(base + OFF_CSRC);
    float* eac   = (float*)(base + OFF_EAC);
    int*   bsum  = (int*)(base + OFF_BSUM);

    (void)hipMemsetAsync(deg, 0, SZ_ZERO, stream);   // deg, cur, gsum

    const int nbN = (N_NODES + SCB - 1) / SCB;

    hist_dst_kernel<<<(N_EDGES + 255) / 256, 256, 0, stream>>>(ei, deg);
    scan_local<<<nbN, SCB, 0, stream>>>(deg, offs, bsum, N_NODES);
    scan_bsum<<<1, SCB, 0, stream>>>(bsum, nbN, offs + N_NODES);
    scan_addoff<<<nbN, SCB, 0, stream>>>(offs, bsum, N_NODES);
    scatter_cse_kernel<<<(N_EDGES + 255) / 256, 256, 0, stream>>>(ei, ea, offs, cur, csrc, eac);
    goffs_bsearch_kernel<<<(N_GRAPHS + 256) / 256, 256, 0, stream>>>(batch, goffs);

    cast_bf16_kernel<<<(N_NODES * FN + 255) / 256, 256, 0, stream>>>(x, xb, N_NODES * FN);
    transpose_cast<<<(FN * 128 + 255) / 256, 256, 0, stream>>>(embW, embt, FN, 128);

    {
        dim3 g((N_NODES + 127) / 128, 128 / 128);
        gemm_mfma_big<64><<<g, 256, 0, stream>>>(xb, embt, embB, h0b, nullptr,
                                                 N_NODES, 128, 1 | 8);
    }

    bf16* hcurb = h0b;
    bf16* hnextb = h1b;
    for (int l = 0; l < NL; ++l) {
        pack_weights_bt<<<(768 * 128 + 255) / 256, 256, 0, stream>>>(
            attW1 + (size_t)l * 272 * 128, mlpW + (size_t)l * 144 * 128,
            gWhh + (size_t)l * 128 * 384, attb1 + l * 128, mlpb + l * 128,
            gbhh + l * 384, wt, bbig);
        pack_edge_w<<<16, 256, 0, stream>>>(
            attW1 + (size_t)l * 272 * 128 + 256 * 128,
            mlpW + (size_t)l * 144 * 128 + 128 * 128, wpack);
        {
            dim3 g((N_NODES + 127) / 128, 768 / 128);
            gemm_mfma_big<128><<<g, 256, 0, stream>>>(hcurb, wt, bbig, pqmb, ghx,
                                                      N_NODES, 768, 2);
        }
        edge_fused_kernel<<<(N_NODES + 3) / 4, 256, 0, stream>>>(
            pqmb, csrc, eac, wpack, attW2 + (size_t)l * 128, attb2 + l,
            offs, aggrb);
        transpose_cast<<<(128 * 384 + 255) / 256, 256, 0, stream>>>(
            gWih + (size_t)l * 128 * 384, wiht, 128, 384);
        gemm_gru<<<(N_NODES + 63) / 64, 256, 0, stream>>>(
            aggrb, wiht, gbih + l * 384, ghx, hcurb, hnextb, N_NODES);
        bf16* tb = hcurb; hcurb = hnextb; hnextb = tb;
    }

    // readout (h fixed across T -> ctx computed once)
    graph_pool_sum<<<N_GRAPHS, 128, 0, stream>>>(hcurb, goffs, g0b);
    transpose_cast<<<(128 * 128 + 255) / 256, 256, 0, stream>>>(gattW1, wiht, 128, 128);
    {
        dim3 g((N_NODES + 127) / 128, 128 / 128);
        gemm_mfma_big<128><<<g, 256, 0, stream>>>(hcurb, wiht, gattb1, hW1b, nullptr,
                                                  N_NODES, 128, 8);
    }
    node_score2_kernel<<<(N_NODES + 3) / 4, 256, 0, stream>>>(
        hW1b, gattW2, gattb2, batch, es, gsum);
    graph_ctx_kernel<<<N_GRAPHS, 128, 0, stream>>>(hcurb, goffs, es, gsum, ctx);

    dim3 gg((N_GRAPHS + 63) / 64, 384 / 64);
    gemm_f32<<<gg, 256, 0, stream>>>(ctx, ggWih, ggbih, gictx, N_GRAPHS, H, 384);
    gemm_f32<<<gg, 256, 0, stream>>>(g0b, ggWhh, ggbhh, ghr, N_GRAPHS, H, 384);
    gru_elem_kernel<<<((size_t)N_GRAPHS * H + 255) / 256, 256, 0, stream>>>(
        gictx, ghr, g0b, gAb, N_GRAPHS);
    gemm_f32<<<gg, 256, 0, stream>>>(gAb, ggWhh, ggbhh, ghr, N_GRAPHS, H, 384);
    gru_elem_kernel<<<((size_t)N_GRAPHS * H + 255) / 256, 256, 0, stream>>>(
        gictx, ghr, gAb, out, N_GRAPHS);
}